// Round 6
// baseline (915.754 us; speedup 1.0000x reference)
//
#include <hip/hip_runtime.h>

#define NN 100000
#define NE 3200000
#define NIN 16
#define ECH 16
#define F 10
#define FP 16          // padded node row stride = 64 B
#define OC 32
#define CSB 104        // colsum stage-1 blocks
#define BKSH 7         // 128 nodes per bucket
#define NBK 782        // ceil(NN / 128)
#define CH 8192        // edges per binproj block

__device__ __forceinline__ unsigned pk_bf16(float a, float b) {
    unsigned ua = __float_as_uint(a); ua = (ua + 0x7FFFu + ((ua >> 16) & 1u)) >> 16;
    unsigned ub = __float_as_uint(b); ub = (ub + 0x7FFFu + ((ub >> 16) & 1u)) >> 16;
    return ua | (ub << 16);
}
__device__ __forceinline__ float bf_lo(unsigned u) { return __uint_as_float(u << 16); }
__device__ __forceinline__ float bf_hi(unsigned u) { return __uint_as_float(u & 0xFFFF0000u); }

// ---------- bucket histogram (LDS atomics, one global flush per block)
__global__ __launch_bounds__(256) void k_binhist(const int* __restrict__ dst,
                                                 int* __restrict__ bkcnt)
{
    __shared__ int lcnt[NBK];
    int t = threadIdx.x;
    for (int k = t; k < NBK; k += 256) lcnt[k] = 0;
    __syncthreads();
    for (int e = blockIdx.x * 256 + t; e < NE; e += gridDim.x * 256)
        atomicAdd(&lcnt[dst[e] >> BKSH], 1);
    __syncthreads();
    for (int k = t; k < NBK; k += 256) {
        int v = lcnt[k];
        if (v) atomicAdd(&bkcnt[k], v);
    }
}

// ---------- scan of bucket counts
__global__ __launch_bounds__(1024) void k_bkscan(const int* __restrict__ bkcnt,
                                                 int* __restrict__ bkbase)
{
    __shared__ int wsum[16], wscan[16];
    int t = threadIdx.x;
    int v = (t < NBK) ? bkcnt[t] : 0;
    int lane = t & 63, w = t >> 6;
    int inc = v;
    for (int d = 1; d < 64; d <<= 1) { int u = __shfl_up(inc, d); if (lane >= d) inc += u; }
    if (lane == 63) wsum[w] = inc;
    __syncthreads();
    if (t < 16) {
        int u = wsum[t];
        for (int d = 1; d < 16; d <<= 1) { int x2 = __shfl_up(u, d); if (t >= d) u += x2; }
        wscan[t] = u;
    }
    __syncthreads();
    int excl = inc - v + (w > 0 ? wscan[w - 1] : 0);
    if (t < NBK) bkbase[t] = excl;
    if (t == 0) bkbase[NBK] = NE;
}

// ---------- binproj: coalesced ea read + W4 projection + bucketed scatter
__global__ __launch_bounds__(256) void k_binproj(
    const int* __restrict__ src, const int* __restrict__ dst,
    const float* __restrict__ ea,
    const int* __restrict__ bkbase, int* __restrict__ cur,
    const float* __restrict__ W4, const float* __restrict__ b4,
    uint4* __restrict__ tmp_e0, unsigned* __restrict__ tmp_e1,
    unsigned* __restrict__ tmp_sd)
{
    __shared__ int lcnt[NBK];
    __shared__ int lbb[NBK];
    __shared__ float w4[ECH*F], b4s[F];
    int t = threadIdx.x;
    if (t < ECH*F) w4[t] = W4[t];
    if (t < F) b4s[t] = b4[t];
    int e0 = blockIdx.x * CH;
    int e1 = e0 + CH; if (e1 > NE) e1 = NE;
    for (int k = t; k < NBK; k += 256) lcnt[k] = 0;
    __syncthreads();
    for (int e = e0 + t; e < e1; e += 256)
        atomicAdd(&lcnt[dst[e] >> BKSH], 1);
    __syncthreads();
    for (int k = t; k < NBK; k += 256) {
        int c = lcnt[k];
        lbb[k] = c ? (bkbase[k] + atomicAdd(&cur[k], c)) : 0;
        lcnt[k] = 0;                       // reuse as local cursor
    }
    __syncthreads();
    for (int e = e0 + t; e < e1; e += 256) {
        int d = dst[e];
        int bk = d >> BKSH;
        const float4* q = (const float4*)(ea + (size_t)e * ECH);
        float4 a0 = q[0], a1 = q[1], a2 = q[2], a3 = q[3];
        float av[ECH] = {a0.x,a0.y,a0.z,a0.w, a1.x,a1.y,a1.z,a1.w,
                         a2.x,a2.y,a2.z,a2.w, a3.x,a3.y,a3.z,a3.w};
        float ev[F];
#pragma unroll
        for (int j = 0; j < F; ++j) ev[j] = b4s[j];
#pragma unroll
        for (int i = 0; i < ECH; ++i) {
            float ai = av[i];
#pragma unroll
            for (int j = 0; j < F; ++j) ev[j] = fmaf(ai, w4[i*F + j], ev[j]);
        }
#pragma unroll
        for (int j = 0; j < F; ++j) ev[j] = fmaxf(ev[j], 0.f);
        int idx = atomicAdd(&lcnt[bk], 1);
        int pos = lbb[bk] + idx;
        tmp_e0[pos] = make_uint4(pk_bf16(ev[0],ev[1]), pk_bf16(ev[2],ev[3]),
                                 pk_bf16(ev[4],ev[5]), pk_bf16(ev[6],ev[7]));
        tmp_e1[pos] = pk_bf16(ev[8], ev[9]);
        tmp_sd[pos] = (unsigned)src[e] | ((unsigned)(d & 127) << 17);
    }
}

// ---------- agg + node init: block per bucket, LDS accumulate, fused finish
__global__ __launch_bounds__(256) void k_agg(
    const float* __restrict__ x,
    const uint4* __restrict__ tmp_e0, const unsigned* __restrict__ tmp_e1,
    const unsigned* __restrict__ tmp_sd,
    const int* __restrict__ bkbase,
    const float* __restrict__ W1, const float* __restrict__ b1,
    const float* __restrict__ b2,
    const float* __restrict__ W3, const float* __restrict__ b3,
    float* __restrict__ base, float* __restrict__ feat)
{
    __shared__ float agg[128][F];
    __shared__ float w1[NIN*F], w3s[F*F], bb[F];
    int t = threadIdx.x;
    if (t < NIN*F) w1[t] = W1[t];
    if (t < F*F)   w3s[t] = W3[t];
    if (t < F) bb[t] = b1[t] + b2[t] + b3[t];
    for (int i = t; i < 128*F; i += 256) ((float*)agg)[i] = 0.f;
    __syncthreads();
    int b = blockIdx.x;
    int bas = bkbase[b], cnt = bkbase[b + 1] - bas;
    for (int i = t; i < cnt; i += 256) {
        uint4 h0 = tmp_e0[bas + i];
        unsigned h1 = tmp_e1[bas + i];
        unsigned sd = tmp_sd[bas + i];
        float* row = agg[(sd >> 17) & 127];
        atomicAdd(row + 0, bf_lo(h0.x)); atomicAdd(row + 1, bf_hi(h0.x));
        atomicAdd(row + 2, bf_lo(h0.y)); atomicAdd(row + 3, bf_hi(h0.y));
        atomicAdd(row + 4, bf_lo(h0.z)); atomicAdd(row + 5, bf_hi(h0.z));
        atomicAdd(row + 6, bf_lo(h0.w)); atomicAdd(row + 7, bf_hi(h0.w));
        atomicAdd(row + 8, bf_lo(h1));   atomicAdd(row + 9, bf_hi(h1));
    }
    __syncthreads();
    int n0 = b << BKSH;
    int nodes = NN - n0; if (nodes > 128) nodes = 128;
    if (t < nodes) {
        int n = n0 + t;
        float acc[F];
#pragma unroll
        for (int j = 0; j < F; ++j) acc[j] = bb[j];
#pragma unroll
        for (int i = 0; i < NIN; ++i) {
            float xi = x[(size_t)n * NIN + i];
#pragma unroll
            for (int j = 0; j < F; ++j) acc[j] = fmaf(xi, w1[i*F + j], acc[j]);
        }
#pragma unroll
        for (int i = 0; i < F; ++i) {
            float ai = agg[t][i];
#pragma unroll
            for (int j = 0; j < F; ++j) acc[j] = fmaf(ai, w3s[i*F + j], acc[j]);
        }
        float4* pb = (float4*)(base + (size_t)n * FP);
        pb[0] = make_float4(acc[0], acc[1], acc[2], acc[3]);
        pb[1] = make_float4(acc[4], acc[5], acc[6], acc[7]);
        pb[2] = make_float4(acc[8], acc[9], 0.f, 0.f);
        pb[3] = make_float4(0.f, 0.f, 0.f, 0.f);
        float4* pf = (float4*)(feat + (size_t)n * FP);
        pf[0] = make_float4(fmaxf(acc[0],0.f), fmaxf(acc[1],0.f), fmaxf(acc[2],0.f), fmaxf(acc[3],0.f));
        pf[1] = make_float4(fmaxf(acc[4],0.f), fmaxf(acc[5],0.f), fmaxf(acc[6],0.f), fmaxf(acc[7],0.f));
        pf[2] = make_float4(fmaxf(acc[8],0.f), fmaxf(acc[9],0.f), 0.f, 0.f);
        pf[3] = make_float4(0.f, 0.f, 0.f, 0.f);
    }
}

// ---------- propagation: block per bucket, gather feat[src] + LDS accumulate
__global__ __launch_bounds__(256) void k_iterB(
    const unsigned* __restrict__ tmp_sd, const int* __restrict__ bkbase,
    const float* __restrict__ featO, const float* __restrict__ base,
    const float* __restrict__ W2, float* __restrict__ featN)
{
    __shared__ float agg[128][F];
    __shared__ float w2[F*F];
    int t = threadIdx.x;
    if (t < F*F) w2[t] = W2[t];
    for (int i = t; i < 128*F; i += 256) ((float*)agg)[i] = 0.f;
    __syncthreads();
    int b = blockIdx.x;
    int bas = bkbase[b], cnt = bkbase[b + 1] - bas;
    for (int i = t; i < cnt; i += 256) {
        unsigned sd = tmp_sd[bas + i];
        int s = sd & 0x1FFFF;
        const float4* q = (const float4*)(featO + (size_t)s * FP);
        float4 v0 = q[0], v1 = q[1], v2 = q[2];
        float* row = agg[(sd >> 17) & 127];
        atomicAdd(row + 0, v0.x); atomicAdd(row + 1, v0.y);
        atomicAdd(row + 2, v0.z); atomicAdd(row + 3, v0.w);
        atomicAdd(row + 4, v1.x); atomicAdd(row + 5, v1.y);
        atomicAdd(row + 6, v1.z); atomicAdd(row + 7, v1.w);
        atomicAdd(row + 8, v2.x); atomicAdd(row + 9, v2.y);
    }
    __syncthreads();
    int n0 = b << BKSH;
    int nodes = NN - n0; if (nodes > 128) nodes = 128;
    if (t < nodes) {
        int n = n0 + t;
        const float4* qs = (const float4*)(featO + (size_t)n * FP);
        float4 s0 = qs[0], s1 = qs[1], s2 = qs[2];
        float av[F] = {agg[t][0]+s0.x, agg[t][1]+s0.y, agg[t][2]+s0.z, agg[t][3]+s0.w,
                       agg[t][4]+s1.x, agg[t][5]+s1.y, agg[t][6]+s1.z, agg[t][7]+s1.w,
                       agg[t][8]+s2.x, agg[t][9]+s2.y};
        const float4* pb = (const float4*)(base + (size_t)n * FP);
        float4 c0 = pb[0], c1 = pb[1], c2 = pb[2];
        float acc[F] = {c0.x,c0.y,c0.z,c0.w, c1.x,c1.y,c1.z,c1.w, c2.x,c2.y};
#pragma unroll
        for (int i = 0; i < F; ++i) {
            float ai = av[i];
#pragma unroll
            for (int j = 0; j < F; ++j) acc[j] = fmaf(ai, w2[i*F + j], acc[j]);
        }
        float4* pf = (float4*)(featN + (size_t)n * FP);
        pf[0] = make_float4(fmaxf(acc[0],0.f), fmaxf(acc[1],0.f), fmaxf(acc[2],0.f), fmaxf(acc[3],0.f));
        pf[1] = make_float4(fmaxf(acc[4],0.f), fmaxf(acc[5],0.f), fmaxf(acc[6],0.f), fmaxf(acc[7],0.f));
        pf[2] = make_float4(fmaxf(acc[8],0.f), fmaxf(acc[9],0.f), 0.f, 0.f);
        pf[3] = make_float4(0.f, 0.f, 0.f, 0.f);
    }
}

// ---------- colsum stage 1: atomic-free per-block partials
__global__ __launch_bounds__(256) void k_colsum(
    const float* __restrict__ feat, float* __restrict__ partial)
{
    __shared__ float sm[4][F];
    int t = threadIdx.x;
    float v[F];
#pragma unroll
    for (int j = 0; j < F; ++j) v[j] = 0.f;
    for (int n = blockIdx.x * 256 + t; n < NN; n += CSB * 256) {
        const float4* p = (const float4*)(feat + (size_t)n * FP);
        float4 v0 = p[0], v1 = p[1], v2 = p[2];
        v[0]+=v0.x; v[1]+=v0.y; v[2]+=v0.z; v[3]+=v0.w;
        v[4]+=v1.x; v[5]+=v1.y; v[6]+=v1.z; v[7]+=v1.w;
        v[8]+=v2.x; v[9]+=v2.y;
    }
#pragma unroll
    for (int off = 32; off > 0; off >>= 1) {
#pragma unroll
        for (int j = 0; j < F; ++j) v[j] += __shfl_down(v[j], off);
    }
    int wid = t >> 6;
    if ((t & 63) == 0) {
#pragma unroll
        for (int j = 0; j < F; ++j) sm[wid][j] = v[j];
    }
    __syncthreads();
    if (t < F) {
        float s = sm[0][t] + sm[1][t] + sm[2][t] + sm[3][t];
        partial[blockIdx.x * F + t] = s;
    }
}

// ---------- tiny: gcol = sum(partial); g = gcol@W6+b6; gpart = relu(g)@W5[0:10] + b5
__global__ void k_gsmall(
    const float* __restrict__ partial, const float* __restrict__ W6,
    const float* __restrict__ b6, const float* __restrict__ W5,
    const float* __restrict__ b5, float* __restrict__ gpart)
{
    __shared__ float gcol[F], r1[F];
    int t = threadIdx.x;
    if (t < F) {
        float s = 0.f;
        for (int b = 0; b < CSB; ++b) s += partial[b * F + t];
        gcol[t] = s;
    }
    __syncthreads();
    if (t < F) {
        float acc = b6[t];
        for (int i = 0; i < F; ++i) acc = fmaf(gcol[i], W6[i*F + t], acc);
        r1[t] = acc > 0.f ? acc : 0.f;
    }
    __syncthreads();
    if (t < OC) {
        float acc = b5[t];
        for (int i = 0; i < F; ++i) acc = fmaf(r1[i], W5[i*OC + t], acc);
        gpart[t] = acc;
    }
}

// ---------- output: out = gpart + relu(feat@W7+b7) @ W5[10:20]
__global__ __launch_bounds__(256) void k_out(
    const float* __restrict__ feat, const float* __restrict__ W7,
    const float* __restrict__ b7, const float* __restrict__ W5,
    const float* __restrict__ gpart, float* __restrict__ out)
{
    __shared__ float w7[F*F], bb7[F], w5[F*OC], gp[OC];
    int t = threadIdx.x;
    if (t < F*F) w7[t] = W7[t];
    if (t < F) bb7[t] = b7[t];
    for (int i = t; i < F*OC; i += 256) w5[i] = W5[F*OC + i];
    if (t < OC) gp[t] = gpart[t];
    __syncthreads();
    int n = blockIdx.x * 256 + t;
    if (n >= NN) return;
    const float4* p = (const float4*)(feat + (size_t)n * FP);
    float4 v0 = p[0], v1 = p[1], v2 = p[2];
    float f[F] = {v0.x,v0.y,v0.z,v0.w, v1.x,v1.y,v1.z,v1.w, v2.x,v2.y};
    float h[F];
#pragma unroll
    for (int j = 0; j < F; ++j) h[j] = bb7[j];
#pragma unroll
    for (int i = 0; i < F; ++i) {
        float fi = f[i];
#pragma unroll
        for (int j = 0; j < F; ++j) h[j] = fmaf(fi, w7[i*F + j], h[j]);
    }
#pragma unroll
    for (int j = 0; j < F; ++j) h[j] = h[j] > 0.f ? h[j] : 0.f;
    float o[OC];
#pragma unroll
    for (int k = 0; k < OC; ++k) o[k] = gp[k];
#pragma unroll
    for (int j = 0; j < F; ++j) {
        float hj = h[j];
#pragma unroll
        for (int k = 0; k < OC; ++k) o[k] = fmaf(hj, w5[j*OC + k], o[k]);
    }
    float4* po = (float4*)(out + (size_t)n * OC);
#pragma unroll
    for (int k = 0; k < 8; ++k)
        po[k] = make_float4(o[4*k], o[4*k+1], o[4*k+2], o[4*k+3]);
}

extern "C" void kernel_launch(void* const* d_in, const int* in_sizes, int n_in,
                              void* d_out, int out_size, void* d_ws, size_t ws_size,
                              hipStream_t stream)
{
    const float* x   = (const float*)d_in[0];
    const int*   ei  = (const int*)d_in[1];
    const float* ea  = (const float*)d_in[2];
    const float* W1  = (const float*)d_in[3];
    const float* b1  = (const float*)d_in[4];
    const float* W2  = (const float*)d_in[5];
    const float* b2  = (const float*)d_in[6];
    const float* W3  = (const float*)d_in[7];
    const float* b3  = (const float*)d_in[8];
    const float* W4  = (const float*)d_in[9];
    const float* b4  = (const float*)d_in[10];
    const float* W5  = (const float*)d_in[11];
    const float* b5  = (const float*)d_in[12];
    const float* W6  = (const float*)d_in[13];
    const float* b6  = (const float*)d_in[14];
    const float* W7  = (const float*)d_in[15];
    const float* b7  = (const float*)d_in[16];

    const int* src = ei;            // edge_index[0]
    const int* dst = ei + NE;       // edge_index[1]

    // workspace layout (16B-aligned chunks)
    char* w = (char*)d_ws;
    uint4* tmp_e0   = (uint4*)w;               w += (size_t)NE * 16;       // 51.2 MB
    unsigned* tmp_e1 = (unsigned*)w;           w += (size_t)NE * 4;        // 12.8 MB
    unsigned* tmp_sd = (unsigned*)w;           w += (size_t)NE * 4;        // 12.8 MB
    float* base  = (float*)w;                  w += (size_t)NN * FP * 4;   // 6.4 MB
    float* featA = (float*)w;                  w += (size_t)NN * FP * 4;
    float* featB = (float*)w;                  w += (size_t)NN * FP * 4;
    int* bkcnt   = (int*)w;                    w += (size_t)NBK * 4;       // zeroed
    int* cur     = (int*)w;                    w += (size_t)NBK * 4;       // zeroed (contiguous)
    int* bkbase  = (int*)w;                    w += (size_t)(NBK + 16) * 4;
    float* partial = (float*)w;                w += (size_t)CSB * F * 4;
    float* gpart = (float*)w;                  w += 32 * 4;

    const int NB = (NN + 255) / 256;
    const int SB = (NE + CH - 1) / CH;

    hipMemsetAsync(bkcnt, 0, (size_t)2 * NBK * 4, stream);   // bkcnt + cur

    k_binhist<<<512, 256, 0, stream>>>(dst, bkcnt);
    k_bkscan <<<1, 1024, 0, stream>>>(bkcnt, bkbase);
    k_binproj<<<SB, 256, 0, stream>>>(src, dst, ea, bkbase, cur, W4, b4,
                                      tmp_e0, tmp_e1, tmp_sd);

    k_agg    <<<NBK, 256, 0, stream>>>(x, tmp_e0, tmp_e1, tmp_sd, bkbase,
                                       W1, b1, b2, W3, b3, base, featA);

    k_iterB  <<<NBK, 256, 0, stream>>>(tmp_sd, bkbase, featA, base, W2, featB);
    k_iterB  <<<NBK, 256, 0, stream>>>(tmp_sd, bkbase, featB, base, W2, featA);

    k_colsum <<<CSB, 256, 0, stream>>>(featA, partial);
    k_gsmall <<<1, 64, 0, stream>>>(partial, W6, b6, W5, b5, gpart);
    k_out    <<<NB, 256, 0, stream>>>(featA, W7, b7, W5, gpart, (float*)d_out);
}

// Round 7
// 908.415 us; speedup vs baseline: 1.0081x; 1.0081x over previous
//
#include <hip/hip_runtime.h>

#define NN 100000
#define NE 3200000
#define NIN 16
#define ECH 16
#define F 10
#define FP 16          // padded node row stride = 64 B
#define OC 32
#define CSB 104        // colsum stage-1 blocks
#define BKSH 9         // 512 nodes per bucket
#define BKN 512        // nodes per bucket
#define NBK 196        // ceil(NN / 512)
#define CH 2048        // edges per binproj block

__device__ __forceinline__ unsigned pk_bf16(float a, float b) {
    unsigned ua = __float_as_uint(a); ua = (ua + 0x7FFFu + ((ua >> 16) & 1u)) >> 16;
    unsigned ub = __float_as_uint(b); ub = (ub + 0x7FFFu + ((ub >> 16) & 1u)) >> 16;
    return ua | (ub << 16);
}
__device__ __forceinline__ float bf_lo(unsigned u) { return __uint_as_float(u << 16); }
__device__ __forceinline__ float bf_hi(unsigned u) { return __uint_as_float(u & 0xFFFF0000u); }

// ---------- bucket histogram (LDS atomics, one global flush per block)
__global__ __launch_bounds__(256) void k_binhist(const int* __restrict__ dst,
                                                 int* __restrict__ bkcnt)
{
    __shared__ int lcnt[NBK];
    int t = threadIdx.x;
    if (t < NBK) lcnt[t] = 0;
    __syncthreads();
    for (int e = blockIdx.x * 256 + t; e < NE; e += gridDim.x * 256)
        atomicAdd(&lcnt[dst[e] >> BKSH], 1);
    __syncthreads();
    if (t < NBK) {
        int v = lcnt[t];
        if (v) atomicAdd(&bkcnt[t], v);
    }
}

// ---------- scan of bucket counts (NBK=196 <= 1024)
__global__ __launch_bounds__(1024) void k_bkscan(const int* __restrict__ bkcnt,
                                                 int* __restrict__ bkbase)
{
    __shared__ int wsum[16], wscan[16];
    int t = threadIdx.x;
    int v = (t < NBK) ? bkcnt[t] : 0;
    int lane = t & 63, w = t >> 6;
    int inc = v;
    for (int d = 1; d < 64; d <<= 1) { int u = __shfl_up(inc, d); if (lane >= d) inc += u; }
    if (lane == 63) wsum[w] = inc;
    __syncthreads();
    if (t < 16) {
        int u = wsum[t];
        for (int d = 1; d < 16; d <<= 1) { int x2 = __shfl_up(u, d); if (t >= d) u += x2; }
        wscan[t] = u;
    }
    __syncthreads();
    int excl = inc - v + (w > 0 ? wscan[w - 1] : 0);
    if (t < NBK) bkbase[t] = excl;
    if (t == 0) bkbase[NBK] = NE;
}

// ---------- binproj: coalesced ea stream + W4 projection + bucketed 32B scatter
// ent[2p]   = {bf16 ev[0..7]}
// ent[2p+1] = {bf16 ev[8..9], src | dlocal<<17, 0, 0}
__global__ __launch_bounds__(256) void k_binproj(
    const int* __restrict__ src, const int* __restrict__ dst,
    const float* __restrict__ ea,
    const int* __restrict__ bkbase, int* __restrict__ cur,
    const float* __restrict__ W4, const float* __restrict__ b4,
    uint4* __restrict__ ent)
{
    __shared__ int lcnt[NBK];
    __shared__ int lbb[NBK];
    __shared__ float w4[ECH*F], b4s[F];
    int t = threadIdx.x;
    if (t < ECH*F) w4[t] = W4[t];
    if (t < F) b4s[t] = b4[t];
    if (t < NBK) lcnt[t] = 0;
    int e0 = blockIdx.x * CH;
    int e1 = e0 + CH; if (e1 > NE) e1 = NE;
    __syncthreads();
    for (int e = e0 + t; e < e1; e += 256)
        atomicAdd(&lcnt[dst[e] >> BKSH], 1);
    __syncthreads();
    if (t < NBK) {
        int c = lcnt[t];
        lbb[t] = c ? (bkbase[t] + atomicAdd(&cur[t], c)) : 0;
        lcnt[t] = 0;                       // reuse as local cursor
    }
    __syncthreads();
    for (int e = e0 + t; e < e1; e += 256) {
        int d = dst[e];
        int bk = d >> BKSH;
        const float4* q = (const float4*)(ea + (size_t)e * ECH);
        float4 a0 = q[0], a1 = q[1], a2 = q[2], a3 = q[3];
        float av[ECH] = {a0.x,a0.y,a0.z,a0.w, a1.x,a1.y,a1.z,a1.w,
                         a2.x,a2.y,a2.z,a2.w, a3.x,a3.y,a3.z,a3.w};
        float ev[F];
#pragma unroll
        for (int j = 0; j < F; ++j) ev[j] = b4s[j];
#pragma unroll
        for (int i = 0; i < ECH; ++i) {
            float ai = av[i];
#pragma unroll
            for (int j = 0; j < F; ++j) ev[j] = fmaf(ai, w4[i*F + j], ev[j]);
        }
#pragma unroll
        for (int j = 0; j < F; ++j) ev[j] = fmaxf(ev[j], 0.f);
        int idx = atomicAdd(&lcnt[bk], 1);
        int pos = lbb[bk] + idx;
        unsigned sd = (unsigned)src[e] | ((unsigned)(d & (BKN - 1)) << 17);
        ent[2*(size_t)pos]     = make_uint4(pk_bf16(ev[0],ev[1]), pk_bf16(ev[2],ev[3]),
                                            pk_bf16(ev[4],ev[5]), pk_bf16(ev[6],ev[7]));
        ent[2*(size_t)pos + 1] = make_uint4(pk_bf16(ev[8],ev[9]), sd, 0u, 0u);
    }
}

// ---------- agg + node init: block per bucket, LDS accumulate, fused finish
// also emits compact sd_out[] (coalesced) for the iteration passes
__global__ __launch_bounds__(256) void k_agg(
    const float* __restrict__ x, const uint4* __restrict__ ent,
    const int* __restrict__ bkbase,
    const float* __restrict__ W1, const float* __restrict__ b1,
    const float* __restrict__ b2,
    const float* __restrict__ W3, const float* __restrict__ b3,
    unsigned* __restrict__ sd_out,
    float* __restrict__ base, float* __restrict__ feat)
{
    __shared__ float agg[BKN][F];     // 20 KB
    __shared__ float w1[NIN*F], w3s[F*F], bb[F];
    int t = threadIdx.x;
    if (t < NIN*F) w1[t] = W1[t];
    if (t < F*F)   w3s[t] = W3[t];
    if (t < F) bb[t] = b1[t] + b2[t] + b3[t];
    for (int i = t; i < BKN*F; i += 256) ((float*)agg)[i] = 0.f;
    __syncthreads();
    int b = blockIdx.x;
    int bas = bkbase[b], cnt = bkbase[b + 1] - bas;
    for (int i = t; i < cnt; i += 256) {
        uint4 h0 = ent[2*(size_t)(bas + i)];
        uint4 h1 = ent[2*(size_t)(bas + i) + 1];
        unsigned sd = h1.y;
        sd_out[bas + i] = sd;
        float* row = agg[(sd >> 17) & (BKN - 1)];
        atomicAdd(row + 0, bf_lo(h0.x)); atomicAdd(row + 1, bf_hi(h0.x));
        atomicAdd(row + 2, bf_lo(h0.y)); atomicAdd(row + 3, bf_hi(h0.y));
        atomicAdd(row + 4, bf_lo(h0.z)); atomicAdd(row + 5, bf_hi(h0.z));
        atomicAdd(row + 6, bf_lo(h0.w)); atomicAdd(row + 7, bf_hi(h0.w));
        atomicAdd(row + 8, bf_lo(h1.x)); atomicAdd(row + 9, bf_hi(h1.x));
    }
    __syncthreads();
    int n0 = b << BKSH;
    int nodes = NN - n0; if (nodes > BKN) nodes = BKN;
    for (int u = t; u < nodes; u += 256) {
        int n = n0 + u;
        const float4* px = (const float4*)(x + (size_t)n * NIN);
        float4 x0 = px[0], x1 = px[1], x2 = px[2], x3 = px[3];
        float xv[NIN] = {x0.x,x0.y,x0.z,x0.w, x1.x,x1.y,x1.z,x1.w,
                         x2.x,x2.y,x2.z,x2.w, x3.x,x3.y,x3.z,x3.w};
        float acc[F];
#pragma unroll
        for (int j = 0; j < F; ++j) acc[j] = bb[j];
#pragma unroll
        for (int i = 0; i < NIN; ++i) {
            float xi = xv[i];
#pragma unroll
            for (int j = 0; j < F; ++j) acc[j] = fmaf(xi, w1[i*F + j], acc[j]);
        }
#pragma unroll
        for (int i = 0; i < F; ++i) {
            float ai = agg[u][i];
#pragma unroll
            for (int j = 0; j < F; ++j) acc[j] = fmaf(ai, w3s[i*F + j], acc[j]);
        }
        float4* pb = (float4*)(base + (size_t)n * FP);
        pb[0] = make_float4(acc[0], acc[1], acc[2], acc[3]);
        pb[1] = make_float4(acc[4], acc[5], acc[6], acc[7]);
        pb[2] = make_float4(acc[8], acc[9], 0.f, 0.f);
        pb[3] = make_float4(0.f, 0.f, 0.f, 0.f);
        float4* pf = (float4*)(feat + (size_t)n * FP);
        pf[0] = make_float4(fmaxf(acc[0],0.f), fmaxf(acc[1],0.f), fmaxf(acc[2],0.f), fmaxf(acc[3],0.f));
        pf[1] = make_float4(fmaxf(acc[4],0.f), fmaxf(acc[5],0.f), fmaxf(acc[6],0.f), fmaxf(acc[7],0.f));
        pf[2] = make_float4(fmaxf(acc[8],0.f), fmaxf(acc[9],0.f), 0.f, 0.f);
        pf[3] = make_float4(0.f, 0.f, 0.f, 0.f);
    }
}

// ---------- propagation: block per bucket, gather feat[src] + LDS accumulate
__global__ __launch_bounds__(256) void k_iterB(
    const unsigned* __restrict__ sd, const int* __restrict__ bkbase,
    const float* __restrict__ featO, const float* __restrict__ base,
    const float* __restrict__ W2, float* __restrict__ featN)
{
    __shared__ float agg[BKN][F];     // 20 KB
    __shared__ float w2[F*F];
    int t = threadIdx.x;
    if (t < F*F) w2[t] = W2[t];
    for (int i = t; i < BKN*F; i += 256) ((float*)agg)[i] = 0.f;
    __syncthreads();
    int b = blockIdx.x;
    int bas = bkbase[b], cnt = bkbase[b + 1] - bas;
    for (int i = t; i < cnt; i += 256) {
        unsigned s_d = sd[bas + i];
        int s = s_d & 0x1FFFF;
        const float4* q = (const float4*)(featO + (size_t)s * FP);
        float4 v0 = q[0], v1 = q[1], v2 = q[2];
        float* row = agg[(s_d >> 17) & (BKN - 1)];
        atomicAdd(row + 0, v0.x); atomicAdd(row + 1, v0.y);
        atomicAdd(row + 2, v0.z); atomicAdd(row + 3, v0.w);
        atomicAdd(row + 4, v1.x); atomicAdd(row + 5, v1.y);
        atomicAdd(row + 6, v1.z); atomicAdd(row + 7, v1.w);
        atomicAdd(row + 8, v2.x); atomicAdd(row + 9, v2.y);
    }
    __syncthreads();
    int n0 = b << BKSH;
    int nodes = NN - n0; if (nodes > BKN) nodes = BKN;
    for (int u = t; u < nodes; u += 256) {
        int n = n0 + u;
        const float4* qs = (const float4*)(featO + (size_t)n * FP);
        float4 s0 = qs[0], s1 = qs[1], s2 = qs[2];
        float av[F] = {agg[u][0]+s0.x, agg[u][1]+s0.y, agg[u][2]+s0.z, agg[u][3]+s0.w,
                       agg[u][4]+s1.x, agg[u][5]+s1.y, agg[u][6]+s1.z, agg[u][7]+s1.w,
                       agg[u][8]+s2.x, agg[u][9]+s2.y};
        const float4* pb = (const float4*)(base + (size_t)n * FP);
        float4 c0 = pb[0], c1 = pb[1], c2 = pb[2];
        float acc[F] = {c0.x,c0.y,c0.z,c0.w, c1.x,c1.y,c1.z,c1.w, c2.x,c2.y};
#pragma unroll
        for (int i = 0; i < F; ++i) {
            float ai = av[i];
#pragma unroll
            for (int j = 0; j < F; ++j) acc[j] = fmaf(ai, w2[i*F + j], acc[j]);
        }
        float4* pf = (float4*)(featN + (size_t)n * FP);
        pf[0] = make_float4(fmaxf(acc[0],0.f), fmaxf(acc[1],0.f), fmaxf(acc[2],0.f), fmaxf(acc[3],0.f));
        pf[1] = make_float4(fmaxf(acc[4],0.f), fmaxf(acc[5],0.f), fmaxf(acc[6],0.f), fmaxf(acc[7],0.f));
        pf[2] = make_float4(fmaxf(acc[8],0.f), fmaxf(acc[9],0.f), 0.f, 0.f);
        pf[3] = make_float4(0.f, 0.f, 0.f, 0.f);
    }
}

// ---------- colsum stage 1: atomic-free per-block partials
__global__ __launch_bounds__(256) void k_colsum(
    const float* __restrict__ feat, float* __restrict__ partial)
{
    __shared__ float sm[4][F];
    int t = threadIdx.x;
    float v[F];
#pragma unroll
    for (int j = 0; j < F; ++j) v[j] = 0.f;
    for (int n = blockIdx.x * 256 + t; n < NN; n += CSB * 256) {
        const float4* p = (const float4*)(feat + (size_t)n * FP);
        float4 v0 = p[0], v1 = p[1], v2 = p[2];
        v[0]+=v0.x; v[1]+=v0.y; v[2]+=v0.z; v[3]+=v0.w;
        v[4]+=v1.x; v[5]+=v1.y; v[6]+=v1.z; v[7]+=v1.w;
        v[8]+=v2.x; v[9]+=v2.y;
    }
#pragma unroll
    for (int off = 32; off > 0; off >>= 1) {
#pragma unroll
        for (int j = 0; j < F; ++j) v[j] += __shfl_down(v[j], off);
    }
    int wid = t >> 6;
    if ((t & 63) == 0) {
#pragma unroll
        for (int j = 0; j < F; ++j) sm[wid][j] = v[j];
    }
    __syncthreads();
    if (t < F) {
        float s = sm[0][t] + sm[1][t] + sm[2][t] + sm[3][t];
        partial[blockIdx.x * F + t] = s;
    }
}

// ---------- tiny: gcol = sum(partial); g = gcol@W6+b6; gpart = relu(g)@W5[0:10] + b5
__global__ void k_gsmall(
    const float* __restrict__ partial, const float* __restrict__ W6,
    const float* __restrict__ b6, const float* __restrict__ W5,
    const float* __restrict__ b5, float* __restrict__ gpart)
{
    __shared__ float gcol[F], r1[F];
    int t = threadIdx.x;
    if (t < F) {
        float s = 0.f;
        for (int b = 0; b < CSB; ++b) s += partial[b * F + t];
        gcol[t] = s;
    }
    __syncthreads();
    if (t < F) {
        float acc = b6[t];
        for (int i = 0; i < F; ++i) acc = fmaf(gcol[i], W6[i*F + t], acc);
        r1[t] = acc > 0.f ? acc : 0.f;
    }
    __syncthreads();
    if (t < OC) {
        float acc = b5[t];
        for (int i = 0; i < F; ++i) acc = fmaf(r1[i], W5[i*OC + t], acc);
        gpart[t] = acc;
    }
}

// ---------- output: out = gpart + relu(feat@W7+b7) @ W5[10:20]
__global__ __launch_bounds__(256) void k_out(
    const float* __restrict__ feat, const float* __restrict__ W7,
    const float* __restrict__ b7, const float* __restrict__ W5,
    const float* __restrict__ gpart, float* __restrict__ out)
{
    __shared__ float w7[F*F], bb7[F], w5[F*OC], gp[OC];
    int t = threadIdx.x;
    if (t < F*F) w7[t] = W7[t];
    if (t < F) bb7[t] = b7[t];
    for (int i = t; i < F*OC; i += 256) w5[i] = W5[F*OC + i];
    if (t < OC) gp[t] = gpart[t];
    __syncthreads();
    int n = blockIdx.x * 256 + t;
    if (n >= NN) return;
    const float4* p = (const float4*)(feat + (size_t)n * FP);
    float4 v0 = p[0], v1 = p[1], v2 = p[2];
    float f[F] = {v0.x,v0.y,v0.z,v0.w, v1.x,v1.y,v1.z,v1.w, v2.x,v2.y};
    float h[F];
#pragma unroll
    for (int j = 0; j < F; ++j) h[j] = bb7[j];
#pragma unroll
    for (int i = 0; i < F; ++i) {
        float fi = f[i];
#pragma unroll
        for (int j = 0; j < F; ++j) h[j] = fmaf(fi, w7[i*F + j], h[j]);
    }
#pragma unroll
    for (int j = 0; j < F; ++j) h[j] = h[j] > 0.f ? h[j] : 0.f;
    float o[OC];
#pragma unroll
    for (int k = 0; k < OC; ++k) o[k] = gp[k];
#pragma unroll
    for (int j = 0; j < F; ++j) {
        float hj = h[j];
#pragma unroll
        for (int k = 0; k < OC; ++k) o[k] = fmaf(hj, w5[j*OC + k], o[k]);
    }
    float4* po = (float4*)(out + (size_t)n * OC);
#pragma unroll
    for (int k = 0; k < 8; ++k)
        po[k] = make_float4(o[4*k], o[4*k+1], o[4*k+2], o[4*k+3]);
}

extern "C" void kernel_launch(void* const* d_in, const int* in_sizes, int n_in,
                              void* d_out, int out_size, void* d_ws, size_t ws_size,
                              hipStream_t stream)
{
    const float* x   = (const float*)d_in[0];
    const int*   ei  = (const int*)d_in[1];
    const float* ea  = (const float*)d_in[2];
    const float* W1  = (const float*)d_in[3];
    const float* b1  = (const float*)d_in[4];
    const float* W2  = (const float*)d_in[5];
    const float* b2  = (const float*)d_in[6];
    const float* W3  = (const float*)d_in[7];
    const float* b3  = (const float*)d_in[8];
    const float* W4  = (const float*)d_in[9];
    const float* b4  = (const float*)d_in[10];
    const float* W5  = (const float*)d_in[11];
    const float* b5  = (const float*)d_in[12];
    const float* W6  = (const float*)d_in[13];
    const float* b6  = (const float*)d_in[14];
    const float* W7  = (const float*)d_in[15];
    const float* b7  = (const float*)d_in[16];

    const int* src = ei;            // edge_index[0]
    const int* dst = ei + NE;       // edge_index[1]

    // workspace layout (16B-aligned chunks)
    char* w = (char*)d_ws;
    uint4* ent      = (uint4*)w;               w += (size_t)NE * 32;       // 102.4 MB
    unsigned* sd_out = (unsigned*)w;           w += (size_t)NE * 4;        // 12.8 MB
    float* base  = (float*)w;                  w += (size_t)NN * FP * 4;   // 6.4 MB
    float* featA = (float*)w;                  w += (size_t)NN * FP * 4;
    float* featB = (float*)w;                  w += (size_t)NN * FP * 4;
    int* bkcnt   = (int*)w;                    w += (size_t)NBK * 4;       // zeroed
    int* cur     = (int*)w;                    w += (size_t)NBK * 4;       // zeroed (contiguous)
    int* bkbase  = (int*)w;                    w += (size_t)(NBK + 16) * 4;
    float* partial = (float*)w;                w += (size_t)CSB * F * 4;
    float* gpart = (float*)w;                  w += 32 * 4;

    const int NB = (NN + 255) / 256;
    const int SB = (NE + CH - 1) / CH;         // 1563 binproj blocks

    hipMemsetAsync(bkcnt, 0, (size_t)2 * NBK * 4, stream);   // bkcnt + cur

    k_binhist<<<512, 256, 0, stream>>>(dst, bkcnt);
    k_bkscan <<<1, 1024, 0, stream>>>(bkcnt, bkbase);
    k_binproj<<<SB, 256, 0, stream>>>(src, dst, ea, bkbase, cur, W4, b4, ent);

    k_agg    <<<NBK, 256, 0, stream>>>(x, ent, bkbase, W1, b1, b2, W3, b3,
                                       sd_out, base, featA);

    k_iterB  <<<NBK, 256, 0, stream>>>(sd_out, bkbase, featA, base, W2, featB);
    k_iterB  <<<NBK, 256, 0, stream>>>(sd_out, bkbase, featB, base, W2, featA);

    k_colsum <<<CSB, 256, 0, stream>>>(featA, partial);
    k_gsmall <<<1, 64, 0, stream>>>(partial, W6, b6, W5, b5, gpart);
    k_out    <<<NB, 256, 0, stream>>>(featA, W7, b7, W5, gpart, (float*)d_out);
}